// Round 14
// baseline (251.586 us; speedup 1.0000x reference)
//
#include <hip/hip_runtime.h>

#define DM   768
#define HN   12
#define DKH  64
#define BSZ  2
#define SEQ  2048
#define MROWS (BSZ*SEQ)   // 4096
#define NEGBIG -1.0e9f
#define NSLOT 40          // k-split slots per (b,h)
#define QSCALE 0.18033688011112042f   // 0.125 * log2(e); flash works in exp2 domain

typedef __bf16 bf16;
typedef __bf16 bf16x8 __attribute__((ext_vector_type(8)));
typedef __bf16 bf16x4 __attribute__((ext_vector_type(4)));
typedef float  f32x4  __attribute__((ext_vector_type(4)));
typedef unsigned int uint32;

__device__ __forceinline__ void gload_lds16(const void* g, void* l) {
    __builtin_amdgcn_global_load_lds(
        (const __attribute__((address_space(1))) char*)g,
        (__attribute__((address_space(3))) char*)l, 16, 0, 0);
}

// ---------------- fp32 -> bf16 convert (wq, wk, wv only) ----------------
__global__ __launch_bounds__(256) void cvt3(const float* __restrict__ a, const float* __restrict__ b,
                                            const float* __restrict__ c,
                                            bf16* __restrict__ x, bf16* __restrict__ y,
                                            bf16* __restrict__ z, int n) {
    const float* s; bf16* d;
    if      (blockIdx.y == 0) { s = a; d = x; }
    else if (blockIdx.y == 1) { s = b; d = y; }
    else                      { s = c; d = z; }
    int i = (blockIdx.x * 256 + threadIdx.x) * 4;
    if (i + 3 < n) {
        float4 v = *(const float4*)(s + i);
        bf16x4 o; o[0] = (bf16)v.x; o[1] = (bf16)v.y; o[2] = (bf16)v.z; o[3] = (bf16)v.w;
        *(bf16x4*)(d + i) = o;
    }
}

// ---------------- QKV projection GEMM, fp32 A fused-convert (104.0-run version) ----------------
__global__ __launch_bounds__(256) void gemm_qkv(
    const float* __restrict__ xq, const float* __restrict__ xk, const float* __restrict__ xv,
    const bf16* __restrict__ wq, const bf16* __restrict__ wk, const bf16* __restrict__ wv,
    bf16* __restrict__ qh, bf16* __restrict__ kh, bf16* __restrict__ vt)
{
    __shared__ float Asf[128 * 32];   // 16 KB
    __shared__ bf16  Bs[128 * 32];    // 8 KB

    const float* A; const bf16* Bw; bf16* Out; float qs;
    if      (blockIdx.z == 0) { A = xq; Bw = wq; Out = qh; qs = QSCALE; }
    else if (blockIdx.z == 1) { A = xk; Bw = wk; Out = kh; qs = 1.0f; }
    else                      { A = xv; Bw = wv; Out = vt; qs = 1.0f; }
    const bool vout = (blockIdx.z == 2);

    const int t = threadIdx.x, w = t >> 6, lane = t & 63;
    const int g = lane >> 4, lo = lane & 15;
    const int mt = blockIdx.x * 128, nt = blockIdx.y * 128;
    const int wr = (w >> 1) * 64, wc = (w & 1) * 64;

    f32x4 acc[4][4] = {};

    for (int k0 = 0; k0 < DM; k0 += 32) {
        #pragma unroll
        for (int i = 0; i < 4; i++) {
            int c = i * 256 + t;
            int row = c >> 3, cc = (c & 7) ^ (row & 7);
            gload_lds16(A + (size_t)(mt + row) * DM + k0 + cc * 4, (char*)Asf + c * 16);
        }
        #pragma unroll
        for (int i = 0; i < 2; i++) {
            int c = i * 256 + t;
            int row = c >> 2, col = (c & 3) * 8;
            gload_lds16(Bw + (size_t)(nt + row) * DM + k0 + col, (char*)Bs + c * 16);
        }
        asm volatile("s_waitcnt vmcnt(0)" ::: "memory");
        __syncthreads();

        bf16x8 af[4], bfr[4];
        #pragma unroll
        for (int m = 0; m < 4; m++) {
            int row = wr + m * 16 + lo;            // row&7 == lo&7
            const char* rp = (const char*)Asf + row * 128;
            float4 f0 = *(const float4*)(rp + (((2 * g)     ^ (lo & 7)) << 4));
            float4 f1 = *(const float4*)(rp + (((2 * g + 1) ^ (lo & 7)) << 4));
            bf16x8 a;
            a[0] = (bf16)f0.x; a[1] = (bf16)f0.y; a[2] = (bf16)f0.z; a[3] = (bf16)f0.w;
            a[4] = (bf16)f1.x; a[5] = (bf16)f1.y; a[6] = (bf16)f1.z; a[7] = (bf16)f1.w;
            af[m] = a;
        }
        #pragma unroll
        for (int n = 0; n < 4; n++)
            bfr[n] = *(const bf16x8*)&Bs[(wc + n * 16 + lo) * 32 + g * 8];
        #pragma unroll
        for (int m = 0; m < 4; m++)
            #pragma unroll
            for (int n = 0; n < 4; n++)
                acc[m][n] = __builtin_amdgcn_mfma_f32_16x16x32_bf16(af[m], bfr[n], acc[m][n], 0, 0, 0);
        __syncthreads();
    }

    if (!vout) {
        #pragma unroll
        for (int m = 0; m < 4; m++) {
            #pragma unroll
            for (int n = 0; n < 4; n++) {
                #pragma unroll
                for (int r = 0; r < 4; r++) {
                    int gm = mt + wr + m * 16 + g * 4 + r;
                    int gn = nt + wc + n * 16 + lo;
                    int b = gm >> 11, s = gm & 2047, h = gn >> 6, d = gn & 63;
                    Out[(((size_t)b * HN + h) * SEQ + s) * DKH + d] = (bf16)(acc[m][n][r] * qs);
                }
            }
        }
    } else {
        #pragma unroll
        for (int m = 0; m < 4; m++) {
            #pragma unroll
            for (int n = 0; n < 4; n++) {
                int gm = mt + wr + m * 16 + g * 4;   // s, 4-aligned
                int gn = nt + wc + n * 16 + lo;
                int b = gm >> 11, s0 = gm & 2047, h = gn >> 6, d = gn & 63;
                bf16x4 pk;
                #pragma unroll
                for (int r = 0; r < 4; r++) pk[r] = (bf16)acc[m][n][r];
                *(bf16x4*)&Out[(((size_t)b * HN + h) * DKH + d) * SEQ + s0] = pk;
            }
        }
    }
}

// ---------------- output projection GEMM (ctx bf16 x Wo fp32 fused; 104.0-run version) ----------------
__global__ __launch_bounds__(256) void gemm_out(
    const bf16* __restrict__ Actx, const float* __restrict__ Bw, float* __restrict__ Out)
{
    __shared__ bf16  As[128 * 32];    // 8 KB
    __shared__ float Bsf[128 * 32];   // 16 KB

    const int t = threadIdx.x, w = t >> 6, lane = t & 63;
    const int g = lane >> 4, lo = lane & 15;
    const int mt = blockIdx.x * 128, nt = blockIdx.y * 128;
    const int wr = (w >> 1) * 64, wc = (w & 1) * 64;

    f32x4 acc[4][4] = {};

    for (int k0 = 0; k0 < DM; k0 += 32) {
        #pragma unroll
        for (int i = 0; i < 2; i++) {
            int c = i * 256 + t;
            int row = c >> 2, col = (c & 3) * 8;
            gload_lds16(Actx + (size_t)(mt + row) * DM + k0 + col, (char*)As + c * 16);
        }
        #pragma unroll
        for (int i = 0; i < 4; i++) {
            int c = i * 256 + t;
            int row = c >> 3, cc = (c & 7) ^ (row & 7);
            gload_lds16(Bw + (size_t)(nt + row) * DM + k0 + cc * 4, (char*)Bsf + c * 16);
        }
        asm volatile("s_waitcnt vmcnt(0)" ::: "memory");
        __syncthreads();

        bf16x8 af[4], bfr[4];
        #pragma unroll
        for (int m = 0; m < 4; m++)
            af[m] = *(const bf16x8*)&As[(wr + m * 16 + lo) * 32 + g * 8];
        #pragma unroll
        for (int n = 0; n < 4; n++) {
            const char* rp = (const char*)Bsf + (wc + n * 16 + lo) * 128;
            float4 f0 = *(const float4*)(rp + (((2 * g)     ^ (lo & 7)) << 4));
            float4 f1 = *(const float4*)(rp + (((2 * g + 1) ^ (lo & 7)) << 4));
            bf16x8 b;
            b[0] = (bf16)f0.x; b[1] = (bf16)f0.y; b[2] = (bf16)f0.z; b[3] = (bf16)f0.w;
            b[4] = (bf16)f1.x; b[5] = (bf16)f1.y; b[6] = (bf16)f1.z; b[7] = (bf16)f1.w;
            bfr[n] = b;
        }
        #pragma unroll
        for (int m = 0; m < 4; m++)
            #pragma unroll
            for (int n = 0; n < 4; n++)
                acc[m][n] = __builtin_amdgcn_mfma_f32_16x16x32_bf16(af[m], bfr[n], acc[m][n], 0, 0, 0);
        __syncthreads();
    }

    #pragma unroll
    for (int m = 0; m < 4; m++) {
        #pragma unroll
        for (int n = 0; n < 4; n++) {
            #pragma unroll
            for (int r = 0; r < 4; r++) {
                int gm = mt + wr + m * 16 + g * 4 + r;
                int gn = nt + wc + n * 16 + lo;
                Out[(size_t)gm * DM + gn] = acc[m][n][r];
            }
        }
    }
}

// ---------------- causal flash attention + FUSED combine, QBLK=128, KVBLK=64 ----------------
// Inner loop identical to the 104.0-run kernel. K-split partials as before; the
// LAST part of each (bh,qt) (device-scope atomic counter) performs the combine
// in-kernel (order-independent math -> deterministic), eliminating the separate
// flash_combine dispatch + launch gap.
__global__ __launch_bounds__(256, 3) void flash_split(
    const bf16* __restrict__ qh, const bf16* __restrict__ kh,
    const bf16* __restrict__ vt, bf16* __restrict__ ctx,
    bf16* __restrict__ pO, float* __restrict__ pM, float* __restrict__ pL,
    unsigned int* __restrict__ pCnt)
{
    __shared__ bf16 Ks[2][4096];     // 16 KB
    __shared__ bf16 Vs[2][4096];     // 16 KB
    __shared__ bf16 pl[4][1024];     // 8 KB: per-wave P [16 q][64 key] swizzled
    __shared__ int lastFlag;

    const int bid = blockIdx.x;
    const int slot = bid / 24;       // heavy slots dispatch first
    const int bh = bid % 24;

    // slot -> (qt, part, nparts)
    int qt, p, np;
    if (slot < 16)      { qt = 15 - (slot >> 2); p = slot & 3;  np = 4; }
    else if (slot < 28) { int s = slot - 16; qt = 11 - s / 3; p = s % 3; np = 3; }
    else if (slot < 36) { int s = slot - 28; qt = 7 - (s >> 1); p = s & 1; np = 2; }
    else                { qt = 39 - slot; p = 0; np = 1; }

    const int T = 2 * qt + 2;
    const int bse = T / np, rem = T - bse * np;
    const int cnt   = bse + (p < rem ? 1 : 0);
    const int start = p * bse + (p < rem ? p : rem);

    const int qb = qt * 128;
    const int t = threadIdx.x, w = t >> 6, lane = t & 63;
    const int g = lane >> 4, lo = lane & 15;
    const size_t base = (size_t)bh * SEQ * DKH;
    const char* khead = (const char*)(kh + base);
    const char* vhead = (const char*)(vt + base);

    uint32 koff[2], voff[2];
    #pragma unroll
    for (int i = 0; i < 2; i++) {
        int c = w * 128 + i * 64 + lane;
        int r = c >> 3, s = c & 7;
        int sw = s ^ (r & 7);
        koff[i] = (uint32)(r * 128  + 16 * sw);   // K: row stride 128 B
        voff[i] = (uint32)(r * 4096 + 16 * sw);   // V^T: row stride SEQ*2 B
    }
    const uint32 kr0 = (uint32)(128 * lo + 16 * (g ^ (lo & 7)));
    const uint32 kr1 = kr0 ^ 64;

    uint32 pw[4], pr[2];
    #pragma unroll
    for (int cg = 0; cg < 4; cg++)
        pw[cg] = (uint32)(lo * 128 + (((2 * cg + (g >> 1)) ^ (lo & 7)) << 4) + (g & 1) * 8);
    #pragma unroll
    for (int kq = 0; kq < 2; kq++)
        pr[kq] = (uint32)(lo * 128 + (((4 * kq + g) ^ (lo & 7)) << 4));
    char* plb = (char*)&pl[w][0];

    const int qrow0 = qb + 16 * w + lo;
    const int qrow1 = qb + 64 + 16 * w + lo;
    const bf16* qp0 = qh + base + (size_t)qrow0 * DKH + g * 8;
    const bf16* qp1 = qh + base + (size_t)qrow1 * DKH + g * 8;
    bf16x8 qa0 = *(const bf16x8*)qp0;
    bf16x8 qa1 = *(const bf16x8*)(qp0 + 32);
    bf16x8 qb0 = *(const bf16x8*)qp1;
    bf16x8 qb1 = *(const bf16x8*)(qp1 + 32);

    f32x4 O0[4] = {}, O1[4] = {};
    float m0 = -1e30f, l0 = 0.0f, m1 = -1e30f, l1 = 0.0f;

    #pragma unroll
    for (int i = 0; i < 2; i++) {
        int c16 = (w * 128 + i * 64 + lane) * 16;
        gload_lds16(khead + (size_t)start * 8192 + koff[i], (char*)&Ks[0][0] + c16);
        gload_lds16(vhead + (size_t)start * 128  + voff[i], (char*)&Vs[0][0] + c16);
    }
    asm volatile("s_waitcnt vmcnt(0)" ::: "memory");
    __syncthreads();

    for (int it = 0; it < cnt; ++it) {
        const int kt = start + it;
        const int par = it & 1, nxt = par ^ 1;
        if (it + 1 < cnt) {
            const char* ks = khead + (size_t)(kt + 1) * 8192;
            const char* vs = vhead + (size_t)(kt + 1) * 128;
            #pragma unroll
            for (int i = 0; i < 2; i++) {
                int c16 = (w * 128 + i * 64 + lane) * 16;
                gload_lds16(ks + koff[i], (char*)&Ks[nxt][0] + c16);
                gload_lds16(vs + voff[i], (char*)&Vs[nxt][0] + c16);
            }
        }

        const bool act0  = (kt != T - 1);
        const bool diag0 = (kt == T - 2);
        const bool diag1 = (kt == T - 1);

        const char* Kp = (const char*)&Ks[par][0];
        f32x4 s0[4], s1[4];
        {
            bf16x8 kf0[4], kf1[4];
            #pragma unroll
            for (int cg = 0; cg < 4; cg++) {
                kf0[cg] = *(const bf16x8*)(Kp + cg * 2048 + kr0);
                kf1[cg] = *(const bf16x8*)(Kp + cg * 2048 + kr1);
            }
            __builtin_amdgcn_s_setprio(1);
            if (act0) {
                #pragma unroll
                for (int cg = 0; cg < 4; cg++) {
                    f32x4 z = {0.0f, 0.0f, 0.0f, 0.0f};
                    z = __builtin_amdgcn_mfma_f32_16x16x32_bf16(kf0[cg], qa0, z, 0, 0, 0);
                    z = __builtin_amdgcn_mfma_f32_16x16x32_bf16(kf1[cg], qa1, z, 0, 0, 0);
                    s0[cg] = z;
                }
            }
            #pragma unroll
            for (int cg = 0; cg < 4; cg++) {
                f32x4 z = {0.0f, 0.0f, 0.0f, 0.0f};
                z = __builtin_amdgcn_mfma_f32_16x16x32_bf16(kf0[cg], qb0, z, 0, 0, 0);
                z = __builtin_amdgcn_mfma_f32_16x16x32_bf16(kf1[cg], qb1, z, 0, 0, 0);
                s1[cg] = z;
            }
            __builtin_amdgcn_s_setprio(0);
        }

        if (act0 && diag0) {
            #pragma unroll
            for (int cg = 0; cg < 4; cg++)
                #pragma unroll
                for (int r = 0; r < 4; r++) {
                    int ki = kt * 64 + cg * 16 + 4 * g + r;
                    s0[cg][r] = (ki > qrow0) ? NEGBIG : s0[cg][r];
                }
        }
        if (diag1) {
            #pragma unroll
            for (int cg = 0; cg < 4; cg++)
                #pragma unroll
                for (int r = 0; r < 4; r++) {
                    int ki = kt * 64 + cg * 16 + 4 * g + r;
                    s1[cg][r] = (ki > qrow1) ? NEGBIG : s1[cg][r];
                }
        }

        if (act0) {
            float mx = fmaxf(fmaxf(fmaxf(s0[0][0], s0[0][1]), fmaxf(s0[0][2], s0[0][3])),
                             fmaxf(fmaxf(s0[1][0], s0[1][1]), fmaxf(s0[1][2], s0[1][3])));
            mx = fmaxf(mx, fmaxf(fmaxf(fmaxf(s0[2][0], s0[2][1]), fmaxf(s0[2][2], s0[2][3])),
                                 fmaxf(fmaxf(s0[3][0], s0[3][1]), fmaxf(s0[3][2], s0[3][3]))));
            mx = fmaxf(mx, __shfl_xor(mx, 16, 64));
            mx = fmaxf(mx, __shfl_xor(mx, 32, 64));
            if (!__all(mx - m0 <= 8.0f)) {
                float mnew = fmaxf(m0, mx);
                float scl = __builtin_exp2f(m0 - mnew);
                m0 = mnew; l0 *= scl;
                float s4[4];
                #pragma unroll
                for (int r = 0; r < 4; r++) s4[r] = __shfl(scl, 4 * g + r, 64);
                #pragma unroll
                for (int dg = 0; dg < 4; dg++)
                    #pragma unroll
                    for (int r = 0; r < 4; r++) O0[dg][r] *= s4[r];
            }
            float rs = 0.0f;
            #pragma unroll
            for (int cg = 0; cg < 4; cg++)
                #pragma unroll
                for (int r = 0; r < 4; r++) {
                    s0[cg][r] = __builtin_exp2f(s0[cg][r] - m0);
                    rs += s0[cg][r];
                }
            rs += __shfl_xor(rs, 16, 64);
            rs += __shfl_xor(rs, 32, 64);
            l0 += rs;
        }
        {
            float mx = fmaxf(fmaxf(fmaxf(s1[0][0], s1[0][1]), fmaxf(s1[0][2], s1[0][3])),
                             fmaxf(fmaxf(s1[1][0], s1[1][1]), fmaxf(s1[1][2], s1[1][3])));
            mx = fmaxf(mx, fmaxf(fmaxf(fmaxf(s1[2][0], s1[2][1]), fmaxf(s1[2][2], s1[2][3])),
                                 fmaxf(fmaxf(s1[3][0], s1[3][1]), fmaxf(s1[3][2], s1[3][3]))));
            mx = fmaxf(mx, __shfl_xor(mx, 16, 64));
            mx = fmaxf(mx, __shfl_xor(mx, 32, 64));
            if (!__all(mx - m1 <= 8.0f)) {
                float mnew = fmaxf(m1, mx);
                float scl = __builtin_exp2f(m1 - mnew);
                m1 = mnew; l1 *= scl;
                float s4[4];
                #pragma unroll
                for (int r = 0; r < 4; r++) s4[r] = __shfl(scl, 4 * g + r, 64);
                #pragma unroll
                for (int dg = 0; dg < 4; dg++)
                    #pragma unroll
                    for (int r = 0; r < 4; r++) O1[dg][r] *= s4[r];
            }
            float rs = 0.0f;
            #pragma unroll
            for (int cg = 0; cg < 4; cg++)
                #pragma unroll
                for (int r = 0; r < 4; r++) {
                    s1[cg][r] = __builtin_exp2f(s1[cg][r] - m1);
                    rs += s1[cg][r];
                }
            rs += __shfl_xor(rs, 16, 64);
            rs += __shfl_xor(rs, 32, 64);
            l1 += rs;
        }

        // ---- V fragments (shared); P0/PV0 then P1/PV1 through the one pl buffer ----
        const char* Vp = (const char*)&Vs[par][0];
        bf16x8 vv[8];
        #pragma unroll
        for (int kq = 0; kq < 2; kq++)
            #pragma unroll
            for (int dblk = 0; dblk < 4; dblk++)
                vv[kq * 4 + dblk] = *(const bf16x8*)
                    (Vp + (dblk * 16 + lo) * 128 + 16 * ((4 * kq + g) ^ (lo & 7)));

        if (act0) {
            #pragma unroll
            for (int cg = 0; cg < 4; cg++) {
                bf16x4 pk;
                #pragma unroll
                for (int r = 0; r < 4; r++) pk[r] = (bf16)s0[cg][r];
                *(bf16x4*)(plb + pw[cg]) = pk;
            }
        }
        asm volatile("s_waitcnt lgkmcnt(0)" ::: "memory");
        __builtin_amdgcn_sched_barrier(0);
        if (act0) {
            __builtin_amdgcn_s_setprio(1);
            #pragma unroll
            for (int kq = 0; kq < 2; kq++) {
                bf16x8 pa = *(const bf16x8*)(plb + pr[kq]);
                #pragma unroll
                for (int dblk = 0; dblk < 4; dblk++)
                    O0[dblk] = __builtin_amdgcn_mfma_f32_16x16x32_bf16(pa, vv[kq * 4 + dblk], O0[dblk], 0, 0, 0);
            }
            __builtin_amdgcn_s_setprio(0);
        }
        __builtin_amdgcn_sched_barrier(0);
        {
            #pragma unroll
            for (int cg = 0; cg < 4; cg++) {
                bf16x4 pk;
                #pragma unroll
                for (int r = 0; r < 4; r++) pk[r] = (bf16)s1[cg][r];
                *(bf16x4*)(plb + pw[cg]) = pk;
            }
            asm volatile("s_waitcnt lgkmcnt(0)" ::: "memory");
            __builtin_amdgcn_sched_barrier(0);
            __builtin_amdgcn_s_setprio(1);
            #pragma unroll
            for (int kq = 0; kq < 2; kq++) {
                bf16x8 pa = *(const bf16x8*)(plb + pr[kq]);
                #pragma unroll
                for (int dblk = 0; dblk < 4; dblk++)
                    O1[dblk] = __builtin_amdgcn_mfma_f32_16x16x32_bf16(pa, vv[kq * 4 + dblk], O1[dblk], 0, 0, 0);
            }
            __builtin_amdgcn_s_setprio(0);
        }

        asm volatile("s_waitcnt vmcnt(0)" ::: "memory");
        __syncthreads();
    }

    // ---- epilogue ----
    if (np == 1) {
        const int b = bh / HN, h = bh % HN;
        float inv0[4], inv1[4];
        #pragma unroll
        for (int r = 0; r < 4; r++) {
            inv0[r] = 1.0f / __shfl(l0, 4 * g + r, 64);
            inv1[r] = 1.0f / __shfl(l1, 4 * g + r, 64);
        }
        #pragma unroll
        for (int dg = 0; dg < 4; dg++) {
            #pragma unroll
            for (int r = 0; r < 4; r++) {
                int row0 = qb + 16 * w + g * 4 + r;
                int row1 = qb + 64 + 16 * w + g * 4 + r;
                ctx[((size_t)(b * SEQ + row0)) * DM + h * DKH + dg * 16 + lo] =
                    (bf16)(O0[dg][r] * inv0[r]);
                ctx[((size_t)(b * SEQ + row1)) * DM + h * DKH + dg * 16 + lo] =
                    (bf16)(O1[dg][r] * inv1[r]);
            }
        }
        return;
    }

    // write partials
    {
        const int pslot = bh * NSLOT + slot;
        bf16* po = pO + (size_t)pslot * 128 * 64;
        #pragma unroll
        for (int dg = 0; dg < 4; dg++) {
            #pragma unroll
            for (int r = 0; r < 4; r++) {
                int r0 = 16 * w + 4 * g + r;
                po[r0 * 64 + dg * 16 + lo]        = (bf16)O0[dg][r];
                po[(64 + r0) * 64 + dg * 16 + lo] = (bf16)O1[dg][r];
            }
        }
        if (g == 0) {
            pM[pslot * 128 + 16 * w + lo]      = m0;
            pL[pslot * 128 + 16 * w + lo]      = l0;
            pM[pslot * 128 + 64 + 16 * w + lo] = m1;
            pL[pslot * 128 + 64 + 16 * w + lo] = l1;
        }
    }

    // last part of this (bh,qt) combines
    __threadfence();
    if (t == 0) {
        unsigned int old = atomicAdd(&pCnt[bh * 16 + qt], 1u);
        lastFlag = (old == (unsigned int)(np - 1));
    }
    __syncthreads();
    if (!lastFlag) return;
    __threadfence();

    {
        const int s0l = slot - p;             // first slot of this (bh,qt)
        const int row = t >> 1, dh = (t & 1) * 32;
        const int pbase = bh * NSLOT + s0l;

        float mi[4], wi[4];
        float mstar = -1e30f;
        #pragma unroll
        for (int i = 0; i < 4; i++)
            if (i < np) { mi[i] = pM[(pbase + i) * 128 + row]; mstar = fmaxf(mstar, mi[i]); }
        float lsum = 0.0f;
        #pragma unroll
        for (int i = 0; i < 4; i++)
            if (i < np) { wi[i] = __builtin_exp2f(mi[i] - mstar); lsum += wi[i] * pL[(pbase + i) * 128 + row]; }
        const float linv = 1.0f / lsum;

        const int b = bh / HN, h = bh % HN;
        bf16* crow = ctx + ((size_t)(b * SEQ + qb + row)) * DM + h * DKH + dh;

        #pragma unroll
        for (int d0 = 0; d0 < 32; d0 += 8) {
            float acc[8] = {};
            #pragma unroll
            for (int i = 0; i < 4; i++) {
                if (i < np) {
                    bf16x8 o = *(const bf16x8*)&pO[((size_t)(pbase + i) * 128 + row) * 64 + dh + d0];
                    #pragma unroll
                    for (int j = 0; j < 8; j++) acc[j] += wi[i] * (float)o[j];
                }
            }
            bf16x8 ov;
            #pragma unroll
            for (int j = 0; j < 8; j++) ov[j] = (bf16)(acc[j] * linv);
            *(bf16x8*)(crow + d0) = ov;
        }
    }
}

// ---------------- launch ----------------
extern "C" void kernel_launch(void* const* d_in, const int* in_sizes, int n_in,
                              void* d_out, int out_size, void* d_ws, size_t ws_size,
                              hipStream_t stream) {
    const float* q  = (const float*)d_in[0];
    const float* k  = (const float*)d_in[1];
    const float* v  = (const float*)d_in[2];
    const float* wq = (const float*)d_in[4];
    const float* wk = (const float*)d_in[5];
    const float* wv = (const float*)d_in[6];
    const float* wo = (const float*)d_in[7];
    float* out = (float*)d_out;

    const size_t NX = (size_t)MROWS * DM;
    const size_t NW = (size_t)DM * DM;

    bf16* p = (bf16*)d_ws;
    bf16* wqb = p; p += NW;
    bf16* wkb = p; p += NW;
    bf16* wvb = p; p += NW;
    bf16* qhp = p; p += NX;
    bf16* khp = p; p += NX;
    bf16* vtp = p; p += NX;   // V^T heads [b,h,d,s]
    bf16* ctxp = p; p += NX;
    bf16* pO = p; p += (size_t)24 * NSLOT * 128 * 64;
    float* pM = (float*)p;
    float* pL = pM + 24 * NSLOT * 128;
    unsigned int* pCnt = (unsigned int*)(pL + 24 * NSLOT * 128);

    hipMemsetAsync(pCnt, 0, 24 * 16 * sizeof(unsigned int), stream);

    cvt3<<<dim3(NW / 1024, 3), 256, 0, stream>>>(wq, wk, wv, wqb, wkb, wvb, (int)NW);

    gemm_qkv<<<dim3(MROWS / 128, DM / 128, 3), 256, 0, stream>>>(
        q, k, v, wqb, wkb, wvb, qhp, khp, vtp);

    flash_split<<<24 * NSLOT, 256, 0, stream>>>(qhp, khp, vtp, ctxp, pO, pM, pL, pCnt);

    gemm_out<<<dim3(MROWS / 128, DM / 128), 256, 0, stream>>>(ctxp, wo, out);
}

// Round 15
// 103.722 us; speedup vs baseline: 2.4256x; 2.4256x over previous
//
#include <hip/hip_runtime.h>

#define DM   768
#define HN   12
#define DKH  64
#define BSZ  2
#define SEQ  2048
#define MROWS (BSZ*SEQ)   // 4096
#define NEGBIG -1.0e9f
#define NSLOT 40          // k-split slots per (b,h)
#define QSCALE 0.18033688011112042f   // 0.125 * log2(e); flash works in exp2 domain

typedef __bf16 bf16;
typedef __bf16 bf16x8 __attribute__((ext_vector_type(8)));
typedef __bf16 bf16x4 __attribute__((ext_vector_type(4)));
typedef float  f32x4  __attribute__((ext_vector_type(4)));
typedef unsigned int uint32;

__device__ __forceinline__ void gload_lds16(const void* g, void* l) {
    __builtin_amdgcn_global_load_lds(
        (const __attribute__((address_space(1))) char*)g,
        (__attribute__((address_space(3))) char*)l, 16, 0, 0);
}

// ---------------- fp32 -> bf16 convert (weights only) ----------------
__global__ __launch_bounds__(256) void cvt4(const float* __restrict__ a, const float* __restrict__ b,
                                            const float* __restrict__ c, const float* __restrict__ e,
                                            bf16* __restrict__ x, bf16* __restrict__ y,
                                            bf16* __restrict__ z, bf16* __restrict__ u, int n) {
    const float* s; bf16* d;
    if      (blockIdx.y == 0) { s = a; d = x; }
    else if (blockIdx.y == 1) { s = b; d = y; }
    else if (blockIdx.y == 2) { s = c; d = z; }
    else                      { s = e; d = u; }
    int i = (blockIdx.x * 256 + threadIdx.x) * 4;
    if (i + 3 < n) {
        float4 v = *(const float4*)(s + i);
        bf16x4 o; o[0] = (bf16)v.x; o[1] = (bf16)v.y; o[2] = (bf16)v.z; o[3] = (bf16)v.w;
        *(bf16x4*)(d + i) = o;
    }
}

// ---------------- QKV projection GEMM, fp32 A fused-convert ----------------
// A (x) is fp32, DMA-staged into fp32 LDS with XOR-swizzled 16B chunks:
//   LDS chunk (row, cc) holds global floats (row, (cc^(row&7))*4 ..+3).
// B (weights) bf16. Q output pre-scaled by QSCALE.
// Q,K out: [b,h,s,d]. V out: TRANSPOSED [b,h,d,s].
__global__ __launch_bounds__(256) void gemm_qkv(
    const float* __restrict__ xq, const float* __restrict__ xk, const float* __restrict__ xv,
    const bf16* __restrict__ wq, const bf16* __restrict__ wk, const bf16* __restrict__ wv,
    bf16* __restrict__ qh, bf16* __restrict__ kh, bf16* __restrict__ vt)
{
    __shared__ float Asf[128 * 32];   // 16 KB
    __shared__ bf16  Bs[128 * 32];    // 8 KB

    const float* A; const bf16* Bw; bf16* Out; float qs;
    if      (blockIdx.z == 0) { A = xq; Bw = wq; Out = qh; qs = QSCALE; }
    else if (blockIdx.z == 1) { A = xk; Bw = wk; Out = kh; qs = 1.0f; }
    else                      { A = xv; Bw = wv; Out = vt; qs = 1.0f; }
    const bool vout = (blockIdx.z == 2);

    const int t = threadIdx.x, w = t >> 6, lane = t & 63;
    const int g = lane >> 4, lo = lane & 15;
    const int mt = blockIdx.x * 128, nt = blockIdx.y * 128;
    const int wr = (w >> 1) * 64, wc = (w & 1) * 64;

    f32x4 acc[4][4] = {};

    for (int k0 = 0; k0 < DM; k0 += 32) {
        #pragma unroll
        for (int i = 0; i < 4; i++) {
            int c = i * 256 + t;
            int row = c >> 3, cc = (c & 7) ^ (row & 7);
            gload_lds16(A + (size_t)(mt + row) * DM + k0 + cc * 4, (char*)Asf + c * 16);
        }
        #pragma unroll
        for (int i = 0; i < 2; i++) {
            int c = i * 256 + t;
            int row = c >> 2, col = (c & 3) * 8;
            gload_lds16(Bw + (size_t)(nt + row) * DM + k0 + col, (char*)Bs + c * 16);
        }
        asm volatile("s_waitcnt vmcnt(0)" ::: "memory");
        __syncthreads();

        bf16x8 af[4], bfr[4];
        #pragma unroll
        for (int m = 0; m < 4; m++) {
            int row = wr + m * 16 + lo;            // row&7 == lo&7
            const char* rp = (const char*)Asf + row * 128;
            float4 f0 = *(const float4*)(rp + (((2 * g)     ^ (lo & 7)) << 4));
            float4 f1 = *(const float4*)(rp + (((2 * g + 1) ^ (lo & 7)) << 4));
            bf16x8 a;
            a[0] = (bf16)f0.x; a[1] = (bf16)f0.y; a[2] = (bf16)f0.z; a[3] = (bf16)f0.w;
            a[4] = (bf16)f1.x; a[5] = (bf16)f1.y; a[6] = (bf16)f1.z; a[7] = (bf16)f1.w;
            af[m] = a;
        }
        #pragma unroll
        for (int n = 0; n < 4; n++)
            bfr[n] = *(const bf16x8*)&Bs[(wc + n * 16 + lo) * 32 + g * 8];
        #pragma unroll
        for (int m = 0; m < 4; m++)
            #pragma unroll
            for (int n = 0; n < 4; n++)
                acc[m][n] = __builtin_amdgcn_mfma_f32_16x16x32_bf16(af[m], bfr[n], acc[m][n], 0, 0, 0);
        __syncthreads();
    }

    if (!vout) {
        #pragma unroll
        for (int m = 0; m < 4; m++) {
            #pragma unroll
            for (int n = 0; n < 4; n++) {
                #pragma unroll
                for (int r = 0; r < 4; r++) {
                    int gm = mt + wr + m * 16 + g * 4 + r;
                    int gn = nt + wc + n * 16 + lo;
                    int b = gm >> 11, s = gm & 2047, h = gn >> 6, d = gn & 63;
                    Out[(((size_t)b * HN + h) * SEQ + s) * DKH + d] = (bf16)(acc[m][n][r] * qs);
                }
            }
        }
    } else {
        #pragma unroll
        for (int m = 0; m < 4; m++) {
            #pragma unroll
            for (int n = 0; n < 4; n++) {
                int gm = mt + wr + m * 16 + g * 4;   // s, 4-aligned
                int gn = nt + wc + n * 16 + lo;
                int b = gm >> 11, s0 = gm & 2047, h = gn >> 6, d = gn & 63;
                bf16x4 pk;
                #pragma unroll
                for (int r = 0; r < 4; r++) pk[r] = (bf16)acc[m][n][r];
                *(bf16x4*)&Out[(((size_t)b * HN + h) * DKH + d) * SEQ + s0] = pk;
            }
        }
    }
}

// ---------------- output projection GEMM ----------------
__global__ __launch_bounds__(256) void gemm_out(
    const bf16* __restrict__ Actx, const bf16* __restrict__ Bw, float* __restrict__ Out)
{
    __shared__ bf16 As[128 * 32];
    __shared__ bf16 Bs[128 * 32];

    const int t = threadIdx.x, w = t >> 6, lane = t & 63;
    const int mt = blockIdx.x * 128, nt = blockIdx.y * 128;
    const int wr = (w >> 1) * 64, wc = (w & 1) * 64;

    f32x4 acc[4][4] = {};

    for (int k0 = 0; k0 < DM; k0 += 32) {
        #pragma unroll
        for (int i = 0; i < 2; i++) {
            int c = i * 256 + t;
            int row = c >> 2, col = (c & 3) * 8;
            gload_lds16(Actx + (size_t)(mt + row) * DM + k0 + col, (char*)As + c * 16);
            gload_lds16(Bw   + (size_t)(nt + row) * DM + k0 + col, (char*)Bs + c * 16);
        }
        asm volatile("s_waitcnt vmcnt(0)" ::: "memory");
        __syncthreads();

        bf16x8 af[4], bfr[4];
        #pragma unroll
        for (int m = 0; m < 4; m++)
            af[m] = *(const bf16x8*)&As[(wr + m * 16 + (lane & 15)) * 32 + (lane >> 4) * 8];
        #pragma unroll
        for (int n = 0; n < 4; n++)
            bfr[n] = *(const bf16x8*)&Bs[(wc + n * 16 + (lane & 15)) * 32 + (lane >> 4) * 8];
        #pragma unroll
        for (int m = 0; m < 4; m++)
            #pragma unroll
            for (int n = 0; n < 4; n++)
                acc[m][n] = __builtin_amdgcn_mfma_f32_16x16x32_bf16(af[m], bfr[n], acc[m][n], 0, 0, 0);
        __syncthreads();
    }

    #pragma unroll
    for (int m = 0; m < 4; m++) {
        #pragma unroll
        for (int n = 0; n < 4; n++) {
            #pragma unroll
            for (int r = 0; r < 4; r++) {
                int gm = mt + wr + m * 16 + (lane >> 4) * 4 + r;
                int gn = nt + wc + n * 16 + (lane & 15);
                Out[(size_t)gm * DM + gn] = acc[m][n][r];
            }
        }
    }
}

// ---------------- causal flash attention, QBLK=128, KVBLK=64, K-SPLIT ----------------
// exp2 domain (Q pre-scaled). LDS 48 KB -> 3 blocks/CU, launch_bounds(256,3)
// so the register allocator has headroom (round-7 lesson: (256,4) forced spills).
// Per-wave pl: two swizzled 2 KB P buffers (one per q-group) -> both P writes
// drain under one lgkmcnt, PVs share V fragments.
__global__ __launch_bounds__(256, 3) void flash_split(
    const bf16* __restrict__ qh, const bf16* __restrict__ kh,
    const bf16* __restrict__ vt, bf16* __restrict__ ctx,
    bf16* __restrict__ pO, float* __restrict__ pM, float* __restrict__ pL)
{
    __shared__ bf16 Ks[2][4096];     // 16 KB
    __shared__ bf16 Vs[2][4096];     // 16 KB
    __shared__ bf16 pl[4][2048];     // 16 KB: per-wave 2 x (16q x 64k) swizzled

    const int bid = blockIdx.x;
    const int slot = bid / 24;       // heavy slots dispatch first
    const int bh = bid % 24;

    // slot -> (qt, part, nparts)
    int qt, p, np;
    if (slot < 16)      { qt = 15 - (slot >> 2); p = slot & 3;  np = 4; }
    else if (slot < 28) { int s = slot - 16; qt = 11 - s / 3; p = s % 3; np = 3; }
    else if (slot < 36) { int s = slot - 28; qt = 7 - (s >> 1); p = s & 1; np = 2; }
    else                { qt = 39 - slot; p = 0; np = 1; }

    const int T = 2 * qt + 2;
    const int bse = T / np, rem = T - bse * np;
    const int cnt   = bse + (p < rem ? 1 : 0);
    const int start = p * bse + (p < rem ? p : rem);

    const int qb = qt * 128;
    const int t = threadIdx.x, w = t >> 6, lane = t & 63;
    const int g = lane >> 4, lo = lane & 15;
    const size_t base = (size_t)bh * SEQ * DKH;
    const char* khead = (const char*)(kh + base);
    const char* vhead = (const char*)(vt + base);

    uint32 koff[2], voff[2];
    #pragma unroll
    for (int i = 0; i < 2; i++) {
        int c = w * 128 + i * 64 + lane;
        int r = c >> 3, s = c & 7;
        int sw = s ^ (r & 7);
        koff[i] = (uint32)(r * 128  + 16 * sw);   // K: row stride 128 B
        voff[i] = (uint32)(r * 4096 + 16 * sw);   // V^T: row stride SEQ*2 B
    }
    const uint32 kr0 = (uint32)(128 * lo + 16 * (g ^ (lo & 7)));
    const uint32 kr1 = kr0 ^ 64;

    uint32 pw[4], pr[2];
    #pragma unroll
    for (int cg = 0; cg < 4; cg++)
        pw[cg] = (uint32)(lo * 128 + (((2 * cg + (g >> 1)) ^ (lo & 7)) << 4) + (g & 1) * 8);
    #pragma unroll
    for (int kq = 0; kq < 2; kq++)
        pr[kq] = (uint32)(lo * 128 + (((4 * kq + g) ^ (lo & 7)) << 4));
    char* plb = (char*)&pl[w][0];

    const int qrow0 = qb + 16 * w + lo;
    const int qrow1 = qb + 64 + 16 * w + lo;
    const bf16* qp0 = qh + base + (size_t)qrow0 * DKH + g * 8;
    const bf16* qp1 = qh + base + (size_t)qrow1 * DKH + g * 8;
    bf16x8 qa0 = *(const bf16x8*)qp0;
    bf16x8 qa1 = *(const bf16x8*)(qp0 + 32);
    bf16x8 qb0 = *(const bf16x8*)qp1;
    bf16x8 qb1 = *(const bf16x8*)(qp1 + 32);

    f32x4 O0[4] = {}, O1[4] = {};
    float m0 = -1e30f, l0 = 0.0f, m1 = -1e30f, l1 = 0.0f;

    #pragma unroll
    for (int i = 0; i < 2; i++) {
        int c16 = (w * 128 + i * 64 + lane) * 16;
        gload_lds16(khead + (size_t)start * 8192 + koff[i], (char*)&Ks[0][0] + c16);
        gload_lds16(vhead + (size_t)start * 128  + voff[i], (char*)&Vs[0][0] + c16);
    }
    asm volatile("s_waitcnt vmcnt(0)" ::: "memory");
    __syncthreads();

    for (int it = 0; it < cnt; ++it) {
        const int kt = start + it;
        const int par = it & 1, nxt = par ^ 1;
        if (it + 1 < cnt) {
            const char* ks = khead + (size_t)(kt + 1) * 8192;
            const char* vs = vhead + (size_t)(kt + 1) * 128;
            #pragma unroll
            for (int i = 0; i < 2; i++) {
                int c16 = (w * 128 + i * 64 + lane) * 16;
                gload_lds16(ks + koff[i], (char*)&Ks[nxt][0] + c16);
                gload_lds16(vs + voff[i], (char*)&Vs[nxt][0] + c16);
            }
        }

        const bool act0  = (kt != T - 1);
        const bool diag0 = (kt == T - 2);
        const bool diag1 = (kt == T - 1);

        const char* Kp = (const char*)&Ks[par][0];
        f32x4 s0[4], s1[4];
        {
            bf16x8 kf0[4], kf1[4];
            #pragma unroll
            for (int cg = 0; cg < 4; cg++) {
                kf0[cg] = *(const bf16x8*)(Kp + cg * 2048 + kr0);
                kf1[cg] = *(const bf16x8*)(Kp + cg * 2048 + kr1);
            }
            __builtin_amdgcn_s_setprio(1);
            if (act0) {
                #pragma unroll
                for (int cg = 0; cg < 4; cg++) {
                    f32x4 z = {0.0f, 0.0f, 0.0f, 0.0f};
                    z = __builtin_amdgcn_mfma_f32_16x16x32_bf16(kf0[cg], qa0, z, 0, 0, 0);
                    z = __builtin_amdgcn_mfma_f32_16x16x32_bf16(kf1[cg], qa1, z, 0, 0, 0);
                    s0[cg] = z;
                }
            }
            #pragma unroll
            for (int cg = 0; cg < 4; cg++) {
                f32x4 z = {0.0f, 0.0f, 0.0f, 0.0f};
                z = __builtin_amdgcn_mfma_f32_16x16x32_bf16(kf0[cg], qb0, z, 0, 0, 0);
                z = __builtin_amdgcn_mfma_f32_16x16x32_bf16(kf1[cg], qb1, z, 0, 0, 0);
                s1[cg] = z;
            }
            __builtin_amdgcn_s_setprio(0);
        }

        if (act0 && diag0) {
            #pragma unroll
            for (int cg = 0; cg < 4; cg++)
                #pragma unroll
                for (int r = 0; r < 4; r++) {
                    int ki = kt * 64 + cg * 16 + 4 * g + r;
                    s0[cg][r] = (ki > qrow0) ? NEGBIG : s0[cg][r];
                }
        }
        if (diag1) {
            #pragma unroll
            for (int cg = 0; cg < 4; cg++)
                #pragma unroll
                for (int r = 0; r < 4; r++) {
                    int ki = kt * 64 + cg * 16 + 4 * g + r;
                    s1[cg][r] = (ki > qrow1) ? NEGBIG : s1[cg][r];
                }
        }

        if (act0) {
            float mx = fmaxf(fmaxf(fmaxf(s0[0][0], s0[0][1]), fmaxf(s0[0][2], s0[0][3])),
                             fmaxf(fmaxf(s0[1][0], s0[1][1]), fmaxf(s0[1][2], s0[1][3])));
            mx = fmaxf(mx, fmaxf(fmaxf(fmaxf(s0[2][0], s0[2][1]), fmaxf(s0[2][2], s0[2][3])),
                                 fmaxf(fmaxf(s0[3][0], s0[3][1]), fmaxf(s0[3][2], s0[3][3]))));
            mx = fmaxf(mx, __shfl_xor(mx, 16, 64));
            mx = fmaxf(mx, __shfl_xor(mx, 32, 64));
            if (!__all(mx - m0 <= 8.0f)) {
                float mnew = fmaxf(m0, mx);
                float scl = __builtin_exp2f(m0 - mnew);
                m0 = mnew; l0 *= scl;
                float s4[4];
                #pragma unroll
                for (int r = 0; r < 4; r++) s4[r] = __shfl(scl, 4 * g + r, 64);
                #pragma unroll
                for (int dg = 0; dg < 4; dg++)
                    #pragma unroll
                    for (int r = 0; r < 4; r++) O0[dg][r] *= s4[r];
            }
            float rs = 0.0f;
            #pragma unroll
            for (int cg = 0; cg < 4; cg++)
                #pragma unroll
                for (int r = 0; r < 4; r++) {
                    s0[cg][r] = __builtin_exp2f(s0[cg][r] - m0);
                    rs += s0[cg][r];
                }
            rs += __shfl_xor(rs, 16, 64);
            rs += __shfl_xor(rs, 32, 64);
            l0 += rs;
            #pragma unroll
            for (int cg = 0; cg < 4; cg++) {
                bf16x4 pk;
                #pragma unroll
                for (int r = 0; r < 4; r++) pk[r] = (bf16)s0[cg][r];
                *(bf16x4*)(plb + pw[cg]) = pk;
            }
        }
        {
            float mx = fmaxf(fmaxf(fmaxf(s1[0][0], s1[0][1]), fmaxf(s1[0][2], s1[0][3])),
                             fmaxf(fmaxf(s1[1][0], s1[1][1]), fmaxf(s1[1][2], s1[1][3])));
            mx = fmaxf(mx, fmaxf(fmaxf(fmaxf(s1[2][0], s1[2][1]), fmaxf(s1[2][2], s1[2][3])),
                                 fmaxf(fmaxf(s1[3][0], s1[3][1]), fmaxf(s1[3][2], s1[3][3]))));
            mx = fmaxf(mx, __shfl_xor(mx, 16, 64));
            mx = fmaxf(mx, __shfl_xor(mx, 32, 64));
            if (!__all(mx - m1 <= 8.0f)) {
                float mnew = fmaxf(m1, mx);
                float scl = __builtin_exp2f(m1 - mnew);
                m1 = mnew; l1 *= scl;
                float s4[4];
                #pragma unroll
                for (int r = 0; r < 4; r++) s4[r] = __shfl(scl, 4 * g + r, 64);
                #pragma unroll
                for (int dg = 0; dg < 4; dg++)
                    #pragma unroll
                    for (int r = 0; r < 4; r++) O1[dg][r] *= s4[r];
            }
            float rs = 0.0f;
            #pragma unroll
            for (int cg = 0; cg < 4; cg++)
                #pragma unroll
                for (int r = 0; r < 4; r++) {
                    s1[cg][r] = __builtin_exp2f(s1[cg][r] - m1);
                    rs += s1[cg][r];
                }
            rs += __shfl_xor(rs, 16, 64);
            rs += __shfl_xor(rs, 32, 64);
            l1 += rs;
            #pragma unroll
            for (int cg = 0; cg < 4; cg++) {
                bf16x4 pk;
                #pragma unroll
                for (int r = 0; r < 4; r++) pk[r] = (bf16)s1[cg][r];
                *(bf16x4*)(plb + 2048 + pw[cg]) = pk;
            }
        }

        // ---- V fragments (shared), single drain, PV for both groups ----
        const char* Vp = (const char*)&Vs[par][0];
        bf16x8 vv[8];
        #pragma unroll
        for (int kq = 0; kq < 2; kq++)
            #pragma unroll
            for (int dblk = 0; dblk < 4; dblk++)
                vv[kq * 4 + dblk] = *(const bf16x8*)
                    (Vp + (dblk * 16 + lo) * 128 + 16 * ((4 * kq + g) ^ (lo & 7)));
        asm volatile("s_waitcnt lgkmcnt(0)" ::: "memory");
        __builtin_amdgcn_sched_barrier(0);

        __builtin_amdgcn_s_setprio(1);
        if (act0) {
            #pragma unroll
            for (int kq = 0; kq < 2; kq++) {
                bf16x8 pa = *(const bf16x8*)(plb + pr[kq]);
                #pragma unroll
                for (int dblk = 0; dblk < 4; dblk++)
                    O0[dblk] = __builtin_amdgcn_mfma_f32_16x16x32_bf16(pa, vv[kq * 4 + dblk], O0[dblk], 0, 0, 0);
            }
        }
        #pragma unroll
        for (int kq = 0; kq < 2; kq++) {
            bf16x8 pa = *(const bf16x8*)(plb + 2048 + pr[kq]);
            #pragma unroll
            for (int dblk = 0; dblk < 4; dblk++)
                O1[dblk] = __builtin_amdgcn_mfma_f32_16x16x32_bf16(pa, vv[kq * 4 + dblk], O1[dblk], 0, 0, 0);
        }
        __builtin_amdgcn_s_setprio(0);

        asm volatile("s_waitcnt vmcnt(0)" ::: "memory");
        __syncthreads();
    }

    // ---- epilogue ----
    if (np == 1) {
        const int b = bh / HN, h = bh % HN;
        float inv0[4], inv1[4];
        #pragma unroll
        for (int r = 0; r < 4; r++) {
            inv0[r] = 1.0f / __shfl(l0, 4 * g + r, 64);
            inv1[r] = 1.0f / __shfl(l1, 4 * g + r, 64);
        }
        #pragma unroll
        for (int dg = 0; dg < 4; dg++) {
            #pragma unroll
            for (int r = 0; r < 4; r++) {
                int row0 = qb + 16 * w + g * 4 + r;
                int row1 = qb + 64 + 16 * w + g * 4 + r;
                ctx[((size_t)(b * SEQ + row0)) * DM + h * DKH + dg * 16 + lo] =
                    (bf16)(O0[dg][r] * inv0[r]);
                ctx[((size_t)(b * SEQ + row1)) * DM + h * DKH + dg * 16 + lo] =
                    (bf16)(O1[dg][r] * inv1[r]);
            }
        }
    } else {
        const int pslot = bh * NSLOT + slot;
        bf16* po = pO + (size_t)pslot * 128 * 64;
        #pragma unroll
        for (int dg = 0; dg < 4; dg++) {
            #pragma unroll
            for (int r = 0; r < 4; r++) {
                int r0 = 16 * w + 4 * g + r;
                po[r0 * 64 + dg * 16 + lo]        = (bf16)O0[dg][r];
                po[(64 + r0) * 64 + dg * 16 + lo] = (bf16)O1[dg][r];
            }
        }
        if (g == 0) {
            pM[pslot * 128 + 16 * w + lo]      = m0;
            pL[pslot * 128 + 16 * w + lo]      = l0;
            pM[pslot * 128 + 64 + 16 * w + lo] = m1;
            pL[pslot * 128 + 64 + 16 * w + lo] = l1;
        }
    }
}

// ---------------- combine partials for split q-tiles (qt 4..15), exp2 domain ----------------
__global__ __launch_bounds__(256) void flash_combine(
    const bf16* __restrict__ pO, const float* __restrict__ pM,
    const float* __restrict__ pL, bf16* __restrict__ ctx)
{
    const int bh = blockIdx.x;        // 0..23
    const int qt = 4 + blockIdx.y;    // 4..15
    int np, s0;
    if (qt >= 12)     { np = 4; s0 = (15 - qt) * 4; }
    else if (qt >= 8) { np = 3; s0 = 16 + (11 - qt) * 3; }
    else              { np = 2; s0 = 28 + (7 - qt) * 2; }

    const int t = threadIdx.x;
    const int row = t >> 1, dh = (t & 1) * 32;
    const int pbase = bh * NSLOT + s0;

    float mi[4], wi[4];
    float mstar = -1e30f;
    #pragma unroll
    for (int i = 0; i < 4; i++)
        if (i < np) { mi[i] = pM[(pbase + i) * 128 + row]; mstar = fmaxf(mstar, mi[i]); }
    float lsum = 0.0f;
    #pragma unroll
    for (int i = 0; i < 4; i++)
        if (i < np) { wi[i] = __builtin_exp2f(mi[i] - mstar); lsum += wi[i] * pL[(pbase + i) * 128 + row]; }
    const float linv = 1.0f / lsum;

    const int b = bh / HN, h = bh % HN;
    bf16* crow = ctx + ((size_t)(b * SEQ + qt * 128 + row)) * DM + h * DKH + dh;

    #pragma unroll
    for (int d0 = 0; d0 < 32; d0 += 8) {
        float acc[8] = {};
        #pragma unroll
        for (int i = 0; i < 4; i++) {
            if (i < np) {
                bf16x8 o = *(const bf16x8*)&pO[((size_t)(pbase + i) * 128 + row) * 64 + dh + d0];
                #pragma unroll
                for (int j = 0; j < 8; j++) acc[j] += wi[i] * (float)o[j];
            }
        }
        bf16x8 ov;
        #pragma unroll
        for (int j = 0; j < 8; j++) ov[j] = (bf16)(acc[j] * linv);
        *(bf16x8*)(crow + d0) = ov;
    }
}

// ---------------- launch ----------------
extern "C" void kernel_launch(void* const* d_in, const int* in_sizes, int n_in,
                              void* d_out, int out_size, void* d_ws, size_t ws_size,
                              hipStream_t stream) {
    const float* q  = (const float*)d_in[0];
    const float* k  = (const float*)d_in[1];
    const float* v  = (const float*)d_in[2];
    const float* wq = (const float*)d_in[4];
    const float* wk = (const float*)d_in[5];
    const float* wv = (const float*)d_in[6];
    const float* wo = (const float*)d_in[7];
    float* out = (float*)d_out;

    const size_t NX = (size_t)MROWS * DM;
    const size_t NW = (size_t)DM * DM;

    bf16* p = (bf16*)d_ws;
    bf16* wqb = p; p += NW;
    bf16* wkb = p; p += NW;
    bf16* wvb = p; p += NW;
    bf16* wob = p; p += NW;
    bf16* qhp = p; p += NX;
    bf16* khp = p; p += NX;
    bf16* vtp = p; p += NX;   // V^T heads [b,h,d,s]
    bf16* ctxp = p; p += NX;
    bf16* pO = p; p += (size_t)24 * NSLOT * 128 * 64;
    float* pM = (float*)p;
    float* pL = pM + 24 * NSLOT * 128;

    cvt4<<<dim3(NW / 1024, 4), 256, 0, stream>>>(wq, wk, wv, wo, wqb, wkb, wvb, wob, (int)NW);

    gemm_qkv<<<dim3(MROWS / 128, DM / 128, 3), 256, 0, stream>>>(
        q, k, v, wqb, wkb, wvb, qhp, khp, vtp);

    flash_split<<<24 * NSLOT, 256, 0, stream>>>(qhp, khp, vtp, ctxp, pO, pM, pL);
    flash_combine<<<dim3(24, 12), 256, 0, stream>>>(pO, pM, pL, ctxp);

    gemm_out<<<dim3(MROWS / 128, DM / 128), 256, 0, stream>>>(ctxp, wob, out);
}